// Round 1
// 2241.714 us; speedup vs baseline: 1.0908x; 1.0908x over previous
//
#include <hip/hip_runtime.h>

#define Bq 4
#define Lseq 2048
#define Dm 1024
#define Hh 16
#define DKd 64

typedef __bf16 bf16x8 __attribute__((ext_vector_type(8)));
typedef __bf16 bf16x4 __attribute__((ext_vector_type(4)));
typedef float f32x4 __attribute__((ext_vector_type(4)));
typedef unsigned long long u64;

__device__ __forceinline__ bf16x8 ld_b8(const __bf16* p) { return *(const bf16x8*)p; }

// ---------------- mask -> bitmask (2 MB, L2-resident) ----------------
__global__ __launch_bounds__(256) void maskpack_kernel(const int* __restrict__ mask,
                                                       u64* __restrict__ bits) {
  const int lane = threadIdx.x & 63;
  const long long gw = (long long)blockIdx.x * 4 + (threadIdx.x >> 6);
  const long long nw = (long long)gridDim.x * 4;
  const long long total = (long long)Bq * Lseq * Lseq / 64;  // 262144
  for (long long w = gw; w < total; w += nw) {
    int m = mask[w * 64 + lane];
    u64 b = __ballot(m != 0);
    if (lane == 0) bits[w] = b;
  }
}

// ---------------- W [k][n] fp32 -> Wt [n][k] bf16 (transpose+convert, once) ----
struct WtArgs {
  const float* w[4];
  __bf16* t[4];
};

__global__ __launch_bounds__(256) void wt_kernel(WtArgs a) {
  __shared__ __bf16 sT[64][72];
  const float* W = a.w[blockIdx.z];
  __bf16* T = a.t[blockIdx.z];
  const int k0 = blockIdx.x * 64, n0 = blockIdx.y * 64;
  const int tid = threadIdx.x;
  const int cr = tid >> 4;         // 0..15 (k row within group)
  const int cc = (tid & 15) * 4;   // 0..60 (n col)
#pragma unroll
  for (int i = 0; i < 4; i++) {
    int r = cr + i * 16;
    float4 v = *(const float4*)&W[(size_t)(k0 + r) * 1024 + n0 + cc];
    sT[cc + 0][r] = (__bf16)v.x;
    sT[cc + 1][r] = (__bf16)v.y;
    sT[cc + 2][r] = (__bf16)v.z;
    sT[cc + 3][r] = (__bf16)v.w;
  }
  __syncthreads();
  const int n = tid >> 2;
  const int kc = (tid & 3) * 16;
#pragma unroll
  for (int j = 0; j < 2; j++) {
    bf16x8 o = *(bf16x8*)&sT[n][kc + j * 8];
    *(bf16x8*)&T[(size_t)(n0 + n) * 1024 + k0 + kc + j * 8] = o;
  }
}

// ---------------- fused QKV projection: X[8192,1024]f32 @ Wt^T + b -> [B,H,L,64] bf16
// 128x128 tile, BK=64, 4 waves (2x2), each wave 64x64 out (4x4 frags of 16x16x32)
__global__ __launch_bounds__(256) void qkv_kernel(
    const float* __restrict__ Xq, const float* __restrict__ Xk, const float* __restrict__ Xv,
    const __bf16* __restrict__ Wtq, const __bf16* __restrict__ Wtk, const __bf16* __restrict__ Wtv,
    const float* __restrict__ bq, const float* __restrict__ bk, const float* __restrict__ bv,
    __bf16* __restrict__ Oq, __bf16* __restrict__ Ok, __bf16* __restrict__ Ov) {
  __shared__ alignas(16) __bf16 As[128][72];  // 144B row stride: 16B-aligned, b128-floor banks
  __shared__ alignas(16) __bf16 Bs[128][72];
  const int z = blockIdx.z;
  const float* X = z == 0 ? Xq : z == 1 ? Xk : Xv;
  const __bf16* Wt = z == 0 ? Wtq : z == 1 ? Wtk : Wtv;
  const float* bias = z == 0 ? bq : z == 1 ? bk : bv;
  __bf16* OUT = z == 0 ? Oq : z == 1 ? Ok : Ov;
  const int tid = threadIdx.x;
  const int lane = tid & 63;
  const int l16 = lane & 15, lq = lane >> 4;
  const int wv = tid >> 6;
  const int wr = wv >> 1, wc = wv & 1;
  const int m0 = blockIdx.x * 128, n0 = blockIdx.y * 128;
  f32x4 acc[4][4] = {};
  for (int k0 = 0; k0 < Dm; k0 += 64) {
    __syncthreads();
#pragma unroll
    for (int i = 0; i < 4; i++) {  // A: 128x64 fp32 -> bf16
      int w = tid + 256 * i;
      int r = w >> 3, c = (w & 7) * 8;
      const float* src = &X[(size_t)(m0 + r) * Dm + k0 + c];
      float4 x0 = *(const float4*)src;
      float4 x1 = *(const float4*)(src + 4);
      bf16x8 t;
      t[0] = (__bf16)x0.x; t[1] = (__bf16)x0.y; t[2] = (__bf16)x0.z; t[3] = (__bf16)x0.w;
      t[4] = (__bf16)x1.x; t[5] = (__bf16)x1.y; t[6] = (__bf16)x1.z; t[7] = (__bf16)x1.w;
      *(bf16x8*)&As[r][c] = t;
    }
#pragma unroll
    for (int i = 0; i < 4; i++) {  // B: Wt rows [n][k], already bf16
      int w = tid + 256 * i;
      int r = w >> 3, c = (w & 7) * 8;
      *(bf16x8*)&Bs[r][c] = *(const bf16x8*)&Wt[(size_t)(n0 + r) * Dm + k0 + c];
    }
    __syncthreads();
#pragma unroll
    for (int ks = 0; ks < 2; ks++) {
      bf16x8 a[4], b[4];
#pragma unroll
      for (int mt = 0; mt < 4; mt++) a[mt] = ld_b8(&As[wr * 64 + mt * 16 + l16][ks * 32 + lq * 8]);
#pragma unroll
      for (int nt = 0; nt < 4; nt++) b[nt] = ld_b8(&Bs[wc * 64 + nt * 16 + l16][ks * 32 + lq * 8]);
#pragma unroll
      for (int mt = 0; mt < 4; mt++)
#pragma unroll
        for (int nt = 0; nt < 4; nt++)
          acc[mt][nt] = __builtin_amdgcn_mfma_f32_16x16x32_bf16(a[mt], b[nt], acc[mt][nt], 0, 0, 0);
    }
  }
#pragma unroll
  for (int nt = 0; nt < 4; nt++) {
    int col = n0 + wc * 64 + nt * 16 + l16;
    int h = col >> 6, d = col & 63;
    float bv_ = bias[col];
#pragma unroll
    for (int mt = 0; mt < 4; mt++) {
#pragma unroll
      for (int r = 0; r < 4; r++) {
        int row = m0 + wr * 64 + mt * 16 + lq * 4 + r;
        int bb = row >> 11, l = row & 2047;
        OUT[((((size_t)bb * Hh + h) * Lseq) + l) * DKd + d] = (__bf16)(acc[mt][nt][r] + bv_);
      }
    }
  }
}

// ---------------- fused attention per (b, h, 16 q-rows) ----------------
__global__ __launch_bounds__(256) void attn_kernel(const __bf16* __restrict__ QH,
                                                   const __bf16* __restrict__ KH,
                                                   const __bf16* __restrict__ VH,
                                                   const u64* __restrict__ MB,
                                                   float* __restrict__ ATTN,
                                                   __bf16* __restrict__ CTX) {
  __shared__ alignas(16) __bf16 sS[16][2056];  // scores/probs bf16, 64.2 KB
  __shared__ alignas(16) __bf16 sV[64][72];    // V^T tile, 9 KB
  __shared__ u64 sM[16][32];                   // mask bits, 4 KB
  const int tid = threadIdx.x;
  const int lane = tid & 63, wv = tid >> 6;
  const int l16 = lane & 15, lq = lane >> 4;
  const int q0 = blockIdx.x * 16;
  const int h = blockIdx.y;
  const int b = blockIdx.z;
  const size_t bh = (size_t)b * Hh + h;
  const __bf16* qbh = QH + bh * Lseq * DKd;
  const __bf16* kbh = KH + bh * Lseq * DKd;
  const __bf16* vbh = VH + bh * Lseq * DKd;

  for (int i = tid; i < 16 * 32; i += 256) {
    int r = i >> 5, wdx = i & 31;
    sM[r][wdx] = MB[((size_t)b * Lseq + q0 + r) * 32 + wdx];
  }
  const __bf16* qp = qbh + (size_t)(q0 + l16) * DKd + lq * 8;
  bf16x8 qa0 = ld_b8(qp);
  bf16x8 qa1 = ld_b8(qp + 32);
  __syncthreads();

  // phase 2: S = QK^T/8, mask, -> LDS bf16. wave wv owns cols [wv*512, wv*512+512)
  for (int i = 0; i < 32; i++) {
    int n0 = (wv * 32 + i) * 16;
    const __bf16* kp = kbh + (size_t)(n0 + l16) * DKd + lq * 8;
    bf16x8 kb0 = ld_b8(kp);
    bf16x8 kb1 = ld_b8(kp + 32);
    f32x4 s = {};
    s = __builtin_amdgcn_mfma_f32_16x16x32_bf16(qa0, kb0, s, 0, 0, 0);
    s = __builtin_amdgcn_mfma_f32_16x16x32_bf16(qa1, kb1, s, 0, 0, 0);
    int col = n0 + l16;
    int wdx = n0 >> 6;
    int sh = col & 63;
#pragma unroll
    for (int r = 0; r < 4; r++) {
      int lrow = lq * 4 + r;
      float e = s[r] * 0.125f;
      if (!((sM[lrow][wdx] >> sh) & 1ull)) e = -1e10f;
      sS[lrow][col] = (__bf16)e;
    }
  }
  __syncthreads();

  // phase 3: softmax, write attn (fp32), keep probs bf16 in LDS
  for (int rr = 0; rr < 4; rr++) {
    int r = wv * 4 + rr;
    float mx = -3.0e38f;
    for (int c = lane; c < Lseq; c += 64) mx = fmaxf(mx, (float)sS[r][c]);
#pragma unroll
    for (int off = 32; off > 0; off >>= 1) mx = fmaxf(mx, __shfl_xor(mx, off, 64));
    float sum = 0.f;
    for (int c = lane; c < Lseq; c += 64) {
      float e = __expf((float)sS[r][c] - mx);
      sum += e;
      sS[r][c] = (__bf16)e;
    }
#pragma unroll
    for (int off = 32; off > 0; off >>= 1) sum += __shfl_xor(sum, off, 64);
    float rinv = 1.0f / sum;
    float* arow = ATTN + (bh * Lseq + q0 + r) * Lseq;
    for (int c = lane; c < Lseq; c += 64) {
      float p = (float)sS[r][c] * rinv;
      sS[r][c] = (__bf16)p;
      arow[c] = p;
    }
  }

  // phase 4: O = P @ V, V staged transposed in LDS, wave wv owns d-slice [wv*16, wv*16+16)
  f32x4 oa = {};
  for (int kc = 0; kc < 32; kc++) {
    __syncthreads();
    {
      int k = lane;
      const __bf16* vp = vbh + (size_t)(kc * 64 + k) * DKd + wv * 16;
#pragma unroll
      for (int i = 0; i < 4; i++) {
        bf16x4 v4 = *(const bf16x4*)(vp + i * 4);
#pragma unroll
        for (int n = 0; n < 4; n++) sV[wv * 16 + i * 4 + n][k] = v4[n];
      }
    }
    __syncthreads();
#pragma unroll
    for (int ks = 0; ks < 2; ks++) {
      bf16x8 pa = ld_b8(&sS[l16][kc * 64 + ks * 32 + lq * 8]);
      bf16x8 vb = ld_b8(&sV[wv * 16 + l16][ks * 32 + lq * 8]);
      oa = __builtin_amdgcn_mfma_f32_16x16x32_bf16(pa, vb, oa, 0, 0, 0);
    }
  }
  {
    int d = h * 64 + wv * 16 + l16;
#pragma unroll
    for (int r = 0; r < 4; r++) {
      int row = q0 + lq * 4 + r;
      CTX[((size_t)b * Lseq + row) * (Hh * DKd) + d] = (__bf16)oa[r];
    }
  }
}

// ---------------- out-proj + bias + residual -> Y (pre-LN, fp32, in d_out) ----------------
// Same 128x128 GEMM structure; A = CTX (bf16), B = Wot (bf16 [n][k])
__global__ __launch_bounds__(256) void oproj_kernel(const __bf16* __restrict__ CTX,
                                                    const __bf16* __restrict__ Wt,
                                                    const float* __restrict__ bias,
                                                    const float* __restrict__ RES,
                                                    float* __restrict__ Y) {
  __shared__ alignas(16) __bf16 As[128][72];
  __shared__ alignas(16) __bf16 Bs[128][72];
  const int tid = threadIdx.x;
  const int lane = tid & 63;
  const int l16 = lane & 15, lq = lane >> 4;
  const int wv = tid >> 6;
  const int wr = wv >> 1, wc = wv & 1;
  const int m0 = blockIdx.x * 128, n0 = blockIdx.y * 128;
  f32x4 acc[4][4] = {};
  for (int k0 = 0; k0 < Dm; k0 += 64) {
    __syncthreads();
#pragma unroll
    for (int i = 0; i < 4; i++) {
      int w = tid + 256 * i;
      int r = w >> 3, c = (w & 7) * 8;
      *(bf16x8*)&As[r][c] = *(const bf16x8*)&CTX[(size_t)(m0 + r) * Dm + k0 + c];
    }
#pragma unroll
    for (int i = 0; i < 4; i++) {
      int w = tid + 256 * i;
      int r = w >> 3, c = (w & 7) * 8;
      *(bf16x8*)&Bs[r][c] = *(const bf16x8*)&Wt[(size_t)(n0 + r) * Dm + k0 + c];
    }
    __syncthreads();
#pragma unroll
    for (int ks = 0; ks < 2; ks++) {
      bf16x8 a[4], b[4];
#pragma unroll
      for (int mt = 0; mt < 4; mt++) a[mt] = ld_b8(&As[wr * 64 + mt * 16 + l16][ks * 32 + lq * 8]);
#pragma unroll
      for (int nt = 0; nt < 4; nt++) b[nt] = ld_b8(&Bs[wc * 64 + nt * 16 + l16][ks * 32 + lq * 8]);
#pragma unroll
      for (int mt = 0; mt < 4; mt++)
#pragma unroll
        for (int nt = 0; nt < 4; nt++)
          acc[mt][nt] = __builtin_amdgcn_mfma_f32_16x16x32_bf16(a[mt], b[nt], acc[mt][nt], 0, 0, 0);
    }
  }
#pragma unroll
  for (int nt = 0; nt < 4; nt++) {
    int col = n0 + wc * 64 + nt * 16 + l16;
    float bv_ = bias[col];
#pragma unroll
    for (int mt = 0; mt < 4; mt++) {
#pragma unroll
      for (int r = 0; r < 4; r++) {
        int row = m0 + wr * 64 + mt * 16 + lq * 4 + r;
        size_t o = (size_t)row * Dm + col;
        Y[o] = acc[mt][nt][r] + bv_ + RES[o];
      }
    }
  }
}

// ---------------- in-place LayerNorm over rows of Y ----------------
__global__ __launch_bounds__(256) void ln_kernel(float* __restrict__ Y,
                                                 const float* __restrict__ g,
                                                 const float* __restrict__ bta) {
  __shared__ float red[8];
  const size_t row = blockIdx.x;
  const int tid = threadIdx.x;
  float4 v = ((float4*)(Y + row * Dm))[tid];
  float s = v.x + v.y + v.z + v.w;
  float sq = v.x * v.x + v.y * v.y + v.z * v.z + v.w * v.w;
#pragma unroll
  for (int off = 32; off > 0; off >>= 1) {
    s += __shfl_xor(s, off, 64);
    sq += __shfl_xor(sq, off, 64);
  }
  if ((tid & 63) == 0) {
    red[tid >> 6] = s;
    red[4 + (tid >> 6)] = sq;
  }
  __syncthreads();
  s = red[0] + red[1] + red[2] + red[3];
  sq = red[4] + red[5] + red[6] + red[7];
  float mean = s * (1.0f / Dm);
  float var = sq * (1.0f / Dm) - mean * mean;
  float rs = rsqrtf(var + 1e-6f);
  float4 g4 = ((const float4*)g)[tid];
  float4 b4 = ((const float4*)bta)[tid];
  float4 o;
  o.x = (v.x - mean) * rs * g4.x + b4.x;
  o.y = (v.y - mean) * rs * g4.y + b4.y;
  o.z = (v.z - mean) * rs * g4.z + b4.z;
  o.w = (v.w - mean) * rs * g4.w + b4.w;
  ((float4*)(Y + row * Dm))[tid] = o;
}

extern "C" void kernel_launch(void* const* d_in, const int* in_sizes, int n_in,
                              void* d_out, int out_size, void* d_ws, size_t ws_size,
                              hipStream_t stream) {
  const float* q = (const float*)d_in[0];
  const float* k = (const float*)d_in[1];
  const float* v = (const float*)d_in[2];
  const int* mask = (const int*)d_in[3];
  const float* Wq = (const float*)d_in[4];
  const float* bq = (const float*)d_in[5];
  const float* Wk = (const float*)d_in[6];
  const float* bk = (const float*)d_in[7];
  const float* Wv = (const float*)d_in[8];
  const float* bv = (const float*)d_in[9];
  const float* Wo = (const float*)d_in[10];
  const float* bo = (const float*)d_in[11];
  const float* ln_g = (const float*)d_in[12];
  const float* ln_b = (const float*)d_in[13];

  float* out = (float*)d_out;                  // [B,L,D] fp32
  float* attn = out + (size_t)Bq * Lseq * Dm;  // [B,H,L,L] fp32

  const size_t nbh = (size_t)Bq * Hh * Lseq * DKd;  // 8.4M elems
  __bf16* qh = (__bf16*)d_ws;
  __bf16* kh = qh + nbh;
  __bf16* vh = kh + nbh;
  __bf16* ctx = vh + nbh;
  u64* mbits = (u64*)(ctx + (size_t)Bq * Lseq * Dm);
  __bf16* wqt = (__bf16*)(mbits + (size_t)Bq * Lseq * Lseq / 64);
  __bf16* wkt = wqt + (size_t)1024 * 1024;
  __bf16* wvt = wkt + (size_t)1024 * 1024;
  __bf16* wot = wvt + (size_t)1024 * 1024;

  maskpack_kernel<<<1024, 256, 0, stream>>>(mask, mbits);

  WtArgs wa;
  wa.w[0] = Wq; wa.w[1] = Wk; wa.w[2] = Wv; wa.w[3] = Wo;
  wa.t[0] = wqt; wa.t[1] = wkt; wa.t[2] = wvt; wa.t[3] = wot;
  wt_kernel<<<dim3(16, 16, 4), 256, 0, stream>>>(wa);

  qkv_kernel<<<dim3(64, 8, 3), 256, 0, stream>>>(q, k, v, wqt, wkt, wvt, bq, bk, bv, qh, kh, vh);

  dim3 ga(Lseq / 16, Hh, Bq);
  attn_kernel<<<ga, 256, 0, stream>>>(qh, kh, vh, mbits, attn, ctx);

  oproj_kernel<<<dim3(64, 8), 256, 0, stream>>>(ctx, wot, bo, q, out);
  ln_kernel<<<Bq * Lseq, 256, 0, stream>>>(out, ln_g, ln_b);
}